// Round 2
// baseline (1125.337 us; speedup 1.0000x reference)
//
#include <hip/hip_runtime.h>
#include <hip/hip_bf16.h>
#include <math.h>

typedef unsigned short u16t;
typedef __bf16 bf16x8 __attribute__((ext_vector_type(8)));
typedef float f32x4 __attribute__((ext_vector_type(4)));

#define NBATCH 64
#define NT 384
#define NC 256
#define NHID 682
#define NHIDP 704
#define NTOK (NBATCH * NT)          // 24576
#define NSLOT (2 * NTOK + 1024)     // 50176 (128-padded expert regions worst case)

static __device__ __forceinline__ float bf2f(u16t u) { return __uint_as_float(((unsigned int)u) << 16); }
static __device__ __forceinline__ u16t f2bf(float f) { return __builtin_bit_cast(u16t, __float2bfloat16(f)); }

// async global->LDS, 16B per lane; LDS dest = wave-uniform base + lane*16.
static __device__ __forceinline__ void gload16(const void* gp, void* lp) {
  __builtin_amdgcn_global_load_lds((const __attribute__((address_space(1))) void*)gp,
                                   (__attribute__((address_space(3))) void*)lp, 16, 0, 0);
}

// LDS tile layout: 16B chunks, chunk(row,g) = row*8 + (g ^ (row&7)) (XOR swizzle).

// ---------------- fp32 -> bf16 elementwise convert ----------------
__global__ void k_cvt(const float* __restrict__ src, u16t* __restrict__ dst, int n) {
  int i = blockIdx.x * 256 + threadIdx.x;
  if (i < n) dst[i] = f2bf(src[i]);
}

// ---------------- RMSNorm (fp32 in, bf16 out) ----------------
__global__ __launch_bounds__(64) void k_rms(const float* __restrict__ xin,
                                            const float* __restrict__ wg,
                                            u16t* __restrict__ out) {
  int n = blockIdx.x, l = threadIdx.x;
  const float* xr = xin + (size_t)n * NC;
  float4 xa = *(const float4*)(xr + l * 4);
  float ssq = xa.x * xa.x + xa.y * xa.y + xa.z * xa.z + xa.w * xa.w;
  for (int d = 1; d < 64; d <<= 1) ssq += __shfl_xor(ssq, d, 64);
  float rs = rsqrtf(ssq * (1.f / 256.f) + 1e-6f);
  float4 wa = *(const float4*)(wg + l * 4);
  ushort4 o;
  o.x = f2bf(xa.x * rs * wa.x);
  o.y = f2bf(xa.y * rs * wa.y);
  o.z = f2bf(xa.z * rs * wa.z);
  o.w = f2bf(xa.w * rs * wa.w);
  *(ushort4*)(out + (size_t)n * NC + l * 4) = o;
}

// ---------------- plain GEMM: C_bf16[M,N] = A[M,K] @ B[N,K]^T ----------------
__global__ __launch_bounds__(256) void k_gemm_bt(const u16t* __restrict__ A,
                                                 const u16t* __restrict__ Bw,
                                                 u16t* __restrict__ Co, int K, int N) {
  __shared__ __align__(16) u16t sA[128 * 64];
  __shared__ __align__(16) u16t sB[128 * 64];
  int t = threadIdx.x;
  int m0 = blockIdx.y * 128, n0 = blockIdx.x * 128;
  int w = t >> 6, l = t & 63, quad = l >> 4, lq = l & 15;
  int wm = (w >> 1) * 64, wn = (w & 1) * 64;
  const f32x4 fz = {0.f, 0.f, 0.f, 0.f};
  f32x4 acc[4][4];
  for (int i = 0; i < 4; i++) for (int j = 0; j < 4; j++) acc[i][j] = fz;
  int nk = K >> 6;
  for (int kb = 0; kb < nk; kb++) {
    int k0 = kb << 6;
    for (int i = 0; i < 4; i++) {
      int c = i * 256 + t; int r = c >> 3; int g = (c & 7) ^ (r & 7);
      gload16(A + (size_t)(m0 + r) * K + k0 + g * 8, sA + (size_t)c * 8);
      gload16(Bw + (size_t)(n0 + r) * K + k0 + g * 8, sB + (size_t)c * 8);
    }
    __syncthreads();
    for (int kk = 0; kk < 2; kk++) {
      int gq = kk * 4 + quad;
      bf16x8 af[4], bf[4];
      for (int mi = 0; mi < 4; mi++) { int row = wm + mi * 16 + lq; af[mi] = *(const bf16x8*)(sA + (row * 8 + (gq ^ (row & 7))) * 8); }
      for (int ni = 0; ni < 4; ni++) { int row = wn + ni * 16 + lq; bf[ni] = *(const bf16x8*)(sB + (row * 8 + (gq ^ (row & 7))) * 8); }
      for (int mi = 0; mi < 4; mi++)
        for (int ni = 0; ni < 4; ni++)
          acc[mi][ni] = __builtin_amdgcn_mfma_f32_16x16x32_bf16(af[mi], bf[ni], acc[mi][ni], 0, 0, 0);
    }
    __syncthreads();
  }
  for (int mi = 0; mi < 4; mi++)
    for (int ni = 0; ni < 4; ni++) {
      int gn = n0 + wn + ni * 16 + lq;
      for (int r = 0; r < 4; r++) {
        int gm = m0 + wm + mi * 16 + quad * 4 + r;
        Co[(size_t)gm * N + gn] = f2bf(acc[mi][ni][r]);
      }
    }
}

// ---------------- GEMM + residual: xo_f32 = y @ wo^T + x_f32 ----------------
__global__ __launch_bounds__(256) void k_gemm_wo(const u16t* __restrict__ A,
                                                 const u16t* __restrict__ Bw,
                                                 const float* __restrict__ xin,
                                                 float* __restrict__ xo) {
  __shared__ __align__(16) u16t sA[128 * 64];
  __shared__ __align__(16) u16t sB[128 * 64];
  int t = threadIdx.x;
  int m0 = blockIdx.y * 128, n0 = blockIdx.x * 128;
  int w = t >> 6, l = t & 63, quad = l >> 4, lq = l & 15;
  int wm = (w >> 1) * 64, wn = (w & 1) * 64;
  const f32x4 fz = {0.f, 0.f, 0.f, 0.f};
  f32x4 acc[4][4];
  for (int i = 0; i < 4; i++) for (int j = 0; j < 4; j++) acc[i][j] = fz;
  for (int kb = 0; kb < 4; kb++) {
    int k0 = kb << 6;
    for (int i = 0; i < 4; i++) {
      int c = i * 256 + t; int r = c >> 3; int g = (c & 7) ^ (r & 7);
      gload16(A + (size_t)(m0 + r) * NC + k0 + g * 8, sA + (size_t)c * 8);
      gload16(Bw + (size_t)(n0 + r) * NC + k0 + g * 8, sB + (size_t)c * 8);
    }
    __syncthreads();
    for (int kk = 0; kk < 2; kk++) {
      int gq = kk * 4 + quad;
      bf16x8 af[4], bf[4];
      for (int mi = 0; mi < 4; mi++) { int row = wm + mi * 16 + lq; af[mi] = *(const bf16x8*)(sA + (row * 8 + (gq ^ (row & 7))) * 8); }
      for (int ni = 0; ni < 4; ni++) { int row = wn + ni * 16 + lq; bf[ni] = *(const bf16x8*)(sB + (row * 8 + (gq ^ (row & 7))) * 8); }
      for (int mi = 0; mi < 4; mi++)
        for (int ni = 0; ni < 4; ni++)
          acc[mi][ni] = __builtin_amdgcn_mfma_f32_16x16x32_bf16(af[mi], bf[ni], acc[mi][ni], 0, 0, 0);
    }
    __syncthreads();
  }
  for (int mi = 0; mi < 4; mi++)
    for (int ni = 0; ni < 4; ni++) {
      int gn = n0 + wn + ni * 16 + lq;
      for (int r = 0; r < 4; r++) {
        int gm = m0 + wm + mi * 16 + quad * 4 + r;
        xo[(size_t)gm * NC + gn] = acc[mi][ni][r] + xin[(size_t)gm * NC + gn];
      }
    }
}

// ---------------- RoPE in place on q[N,256] and k[N,128] (bf16) ----------------
__global__ __launch_bounds__(192) void k_rope(u16t* __restrict__ q, u16t* __restrict__ kbuf) {
  int n = blockIdx.x; int t = n % NT;
  int i = threadIdx.x;
  u16t* base; int d;
  if (i < 128) { base = q + (size_t)n * NC + (i >> 5) * 64; d = i & 31; }
  else { int j = i - 128; base = kbuf + (size_t)n * 128 + (j >> 5) * 64; d = j & 31; }
  float x1 = bf2f(base[d]), x2 = bf2f(base[d + 32]);
  float ang = (float)t * powf(10000.f, -(float)d * (1.f / 32.f));
  float s, c; sincosf(ang, &s, &c);
  base[d] = f2bf(x1 * c - x2 * s);
  base[d + 32] = f2bf(x2 * c + x1 * s);
}

// ---------------- flash attention, causal GQA (bf16) ----------------
__global__ __launch_bounds__(256) void k_attn(const u16t* __restrict__ q,
                                              const u16t* __restrict__ kbuf,
                                              const u16t* __restrict__ vbuf,
                                              u16t* __restrict__ y) {
  __shared__ __align__(16) u16t sK[64 * 64];
  __shared__ __align__(16) u16t sVT[64 * 64];
  __shared__ __align__(16) u16t sP[4 * 32 * 64];
  int qt = blockIdx.x, h = blockIdx.y, b = blockIdx.z;
  int kvh = h >> 1;
  int t = threadIdx.x, w = t >> 6, l = t & 63, quad = l >> 4, lq = l & 15;
  int tb = qt * 128 + w * 32;
  bf16x8 qf[2][2];
  for (int mi = 0; mi < 2; mi++)
    for (int kk = 0; kk < 2; kk++)
      qf[mi][kk] = *(const bf16x8*)(q + ((size_t)(b * NT + tb + mi * 16 + lq)) * NC + h * 64 + kk * 32 + quad * 8);
  const f32x4 fz = {0.f, 0.f, 0.f, 0.f};
  f32x4 accO[2][4];
  float mrow[2][4], lrow[2][4];
  for (int mi = 0; mi < 2; mi++)
    for (int ni = 0; ni < 4; ni++) accO[mi][ni] = fz;
  for (int mi = 0; mi < 2; mi++)
    for (int r = 0; r < 4; r++) { mrow[mi][r] = -1e30f; lrow[mi][r] = 0.f; }
  u16t* myP = sP + w * 2048;
  int nkt = (qt + 1) * 2;
  for (int kt = 0; kt < nkt; kt++) {
    int s0 = kt * 64;
    for (int i = 0; i < 2; i++) {
      int c = i * 256 + t; int s = c >> 3; int g = (c & 7) ^ (s & 7);
      gload16(kbuf + ((size_t)(b * NT + s0 + s)) * 128 + kvh * 64 + g * 8, sK + (size_t)c * 8);
    }
    for (int i = 0; i < 2; i++) {
      int p = i * 256 + t; int n0g = p >> 6; int s = p & 63; int n0 = n0g * 8;
      const u16t* vp = vbuf + ((size_t)(b * NT + s0 + s)) * 128 + kvh * 64 + n0;
      ushort4 v0 = *(const ushort4*)vp; ushort4 v1 = *(const ushort4*)(vp + 4);
      u16t vv[8] = {v0.x, v0.y, v0.z, v0.w, v1.x, v1.y, v1.z, v1.w};
      for (int j = 0; j < 8; j++) {
        int nn = n0 + j;
        sVT[(nn * 8 + ((s >> 3) ^ (nn & 7))) * 8 + (s & 7)] = vv[j];
      }
    }
    __syncthreads();
    if (s0 <= tb + 31) {
      f32x4 accS[2][4];
      for (int mi = 0; mi < 2; mi++) for (int ni = 0; ni < 4; ni++) accS[mi][ni] = fz;
      for (int kk = 0; kk < 2; kk++) {
        int gq = kk * 4 + quad;
        bf16x8 kf[4];
        for (int ni = 0; ni < 4; ni++) { int row = ni * 16 + lq; kf[ni] = *(const bf16x8*)(sK + (row * 8 + (gq ^ (row & 7))) * 8); }
        for (int mi = 0; mi < 2; mi++)
          for (int ni = 0; ni < 4; ni++)
            accS[mi][ni] = __builtin_amdgcn_mfma_f32_16x16x32_bf16(qf[mi][kk], kf[ni], accS[mi][ni], 0, 0, 0);
      }
      for (int mi = 0; mi < 2; mi++) {
        float alpha[4];
        for (int r = 0; r < 4; r++) {
          int trow = tb + mi * 16 + quad * 4 + r;
          float mx = -1e30f;
          for (int ni = 0; ni < 4; ni++) {
            int ss = s0 + ni * 16 + lq;
            float sv = accS[mi][ni][r] * 0.125f;
            sv = (ss > trow) ? -1e30f : sv;
            accS[mi][ni][r] = sv;
            mx = fmaxf(mx, sv);
          }
          for (int d = 1; d < 16; d <<= 1) mx = fmaxf(mx, __shfl_xor(mx, d, 64));
          float mnew = fmaxf(mrow[mi][r], mx);
          float al = __expf(mrow[mi][r] - mnew);
          float rsum = 0.f;
          for (int ni = 0; ni < 4; ni++) {
            float p = __expf(accS[mi][ni][r] - mnew);
            accS[mi][ni][r] = p;
            rsum += p;
          }
          for (int d = 1; d < 16; d <<= 1) rsum += __shfl_xor(rsum, d, 64);
          lrow[mi][r] = lrow[mi][r] * al + rsum;
          mrow[mi][r] = mnew;
          alpha[r] = al;
        }
        for (int ni = 0; ni < 4; ni++)
          for (int r = 0; r < 4; r++) accO[mi][ni][r] *= alpha[r];
        for (int ni = 0; ni < 4; ni++) {
          int cc = ni * 16 + lq;
          for (int r = 0; r < 4; r++) {
            int row = mi * 16 + quad * 4 + r;
            myP[((cc >> 3) * 32 + row) * 8 + (cc & 7)] = f2bf(accS[mi][ni][r]);
          }
        }
      }
      asm volatile("s_waitcnt lgkmcnt(0)" ::: "memory");
      for (int kk = 0; kk < 2; kk++) {
        int gq = kk * 4 + quad;
        bf16x8 pf[2], vf[4];
        for (int mi = 0; mi < 2; mi++) { int row = mi * 16 + lq; pf[mi] = *(const bf16x8*)(myP + (gq * 32 + row) * 8); }
        for (int ni = 0; ni < 4; ni++) { int row = ni * 16 + lq; vf[ni] = *(const bf16x8*)(sVT + (row * 8 + (gq ^ (row & 7))) * 8); }
        for (int mi = 0; mi < 2; mi++)
          for (int ni = 0; ni < 4; ni++)
            accO[mi][ni] = __builtin_amdgcn_mfma_f32_16x16x32_bf16(pf[mi], vf[ni], accO[mi][ni], 0, 0, 0);
      }
    }
    __syncthreads();
  }
  for (int mi = 0; mi < 2; mi++)
    for (int r = 0; r < 4; r++) {
      int trow = tb + mi * 16 + quad * 4 + r;
      float inv = 1.f / lrow[mi][r];
      for (int ni = 0; ni < 4; ni++) {
        int d = ni * 16 + lq;
        y[((size_t)(b * NT + trow)) * NC + h * 64 + d] = f2bf(accO[mi][ni][r] * inv);
      }
    }
}

// ---------------- router in fp32: rmsnorm + logits + softmax + top-2 ----------------
__global__ __launch_bounds__(64) void k_router(const float* __restrict__ x2,
                                               const float* __restrict__ ln2w,
                                               const float* __restrict__ rw,
                                               int* __restrict__ eidx, float* __restrict__ ew,
                                               int* __restrict__ cnt) {
  int n = blockIdx.x; int l = threadIdx.x;
  const float* xr = x2 + (size_t)n * NC;
  float4 xa = *(const float4*)(xr + l * 4);
  float ssq = xa.x * xa.x + xa.y * xa.y + xa.z * xa.z + xa.w * xa.w;
  for (int d = 1; d < 64; d <<= 1) ssq += __shfl_xor(ssq, d, 64);
  float rs = rsqrtf(ssq * (1.f / 256.f) + 1e-6f);
  int e = l & 7, ch = l >> 3;
  float acc = 0.f;
  for (int j = 0; j < 32; j++) {
    int c = ch * 32 + j;
    acc += xr[c] * ln2w[c] * rw[(size_t)e * NC + c];
  }
  acc *= rs;
  for (int d = 8; d < 64; d <<= 1) acc += __shfl_xor(acc, d, 64);
  float lg[8];
  for (int ee = 0; ee < 8; ee++) lg[ee] = __shfl(acc, ee, 64);
  if (l == 0) {
    float mx = lg[0];
    for (int ee = 1; ee < 8; ee++) mx = fmaxf(mx, lg[ee]);
    float p[8], sum = 0.f;
    for (int ee = 0; ee < 8; ee++) { p[ee] = __expf(lg[ee] - mx); sum += p[ee]; }
    float inv = 1.f / sum;
    for (int ee = 0; ee < 8; ee++) p[ee] *= inv;
    int i0 = 0; float b0 = p[0];
    for (int ee = 1; ee < 8; ee++) if (p[ee] > b0) { b0 = p[ee]; i0 = ee; }
    int i1 = -1; float b1 = -1.f;
    for (int ee = 0; ee < 8; ee++) if (ee != i0 && p[ee] > b1) { b1 = p[ee]; i1 = ee; }
    float s2 = 1.f / (b0 + b1 + 1e-9f);
    eidx[n * 2] = i0; eidx[n * 2 + 1] = i1;
    ew[n * 2] = b0 * s2; ew[n * 2 + 1] = b1 * s2;
    atomicAdd(&cnt[i0], 1); atomicAdd(&cnt[i1], 1);
  }
}

__global__ void k_init(int* __restrict__ tok, float* __restrict__ tokw, int* __restrict__ ctrl) {
  int i = blockIdx.x * 256 + threadIdx.x;
  if (i < NSLOT) { tok[i] = -1; tokw[i] = 0.f; }
  if (blockIdx.x == 0 && threadIdx.x < 64) ctrl[threadIdx.x] = 0;
}

__global__ void k_scan(const int* __restrict__ cnt, int* __restrict__ offs, int* __restrict__ cursor) {
  if (threadIdx.x == 0) {
    int off = 0;
    for (int e = 0; e < 8; e++) {
      offs[e] = off; cursor[e] = off;
      off += ((cnt[e] + 127) >> 7) << 7;
    }
    offs[8] = off;
  }
}

__global__ void k_scatter(const int* __restrict__ eidx, const float* __restrict__ ew,
                          int* __restrict__ cursor, int* __restrict__ tok, float* __restrict__ tokw) {
  int n = blockIdx.x * 256 + threadIdx.x;
  if (n < NTOK) {
    for (int j = 0; j < 2; j++) {
      int e = eidx[n * 2 + j];
      int pos = atomicAdd(&cursor[e], 1);
      tok[pos] = n; tokw[pos] = ew[n * 2 + j];
    }
  }
}

// pack fp32 w1/w3 -> bf16 [8][704][256] zero-padded rows; w2 -> bf16 [8][256][704] zero-padded cols
__global__ void k_pack13(const float* __restrict__ w1, const float* __restrict__ w3,
                         u16t* __restrict__ w1p, u16t* __restrict__ w3p) {
  int idx = blockIdx.x * 256 + threadIdx.x;
  int kcol = idx & 255; int tmp = idx >> 8; int nrow = tmp % NHIDP; int e = tmp / NHIDP;
  if (nrow < NHID) {
    size_t src = ((size_t)e * NHID + nrow) * NC + kcol;
    w1p[idx] = f2bf(w1[src]); w3p[idx] = f2bf(w3[src]);
  } else { w1p[idx] = 0; w3p[idx] = 0; }
}

__global__ void k_pack2(const float* __restrict__ w2, u16t* __restrict__ w2p) {
  int idx = blockIdx.x * 256 + threadIdx.x;
  int kcol = idx % NHIDP; int tmp = idx / NHIDP; int nrow = tmp & 255; int e = tmp >> 8;
  w2p[idx] = (kcol < NHID) ? f2bf(w2[((size_t)e * NC + nrow) * NHID + kcol]) : (u16t)0;
}

// ---------------- MoE expert GEMM 1: hh = silu(A@w1^T) * (A@w3^T), gathered rows ----------------
__global__ __launch_bounds__(256) void k_moe_e1(const u16t* __restrict__ flat,
                                                const u16t* __restrict__ w1p,
                                                const u16t* __restrict__ w3p,
                                                const int* __restrict__ offs,
                                                const int* __restrict__ tok,
                                                u16t* __restrict__ hh) {
  __shared__ __align__(16) u16t sA[128 * 64];
  __shared__ __align__(16) u16t sB1[64 * 64];
  __shared__ __align__(16) u16t sB3[64 * 64];
  int t = threadIdx.x;
  int slot0 = blockIdx.y * 128, n0 = blockIdx.x * 64;
  int e = 7;
  for (int i = 0; i < 8; i++) { if (slot0 < offs[i + 1]) { e = i; break; } }
  const u16t* B1 = w1p + (size_t)e * NHIDP * NC;
  const u16t* B3 = w3p + (size_t)e * NHIDP * NC;
  int w = t >> 6, l = t & 63, quad = l >> 4, lq = l & 15;
  int wm = (w >> 1) * 64, wn = (w & 1) * 32;
  const f32x4 fz = {0.f, 0.f, 0.f, 0.f};
  f32x4 a1[4][2], a3[4][2];
  for (int i = 0; i < 4; i++) for (int j = 0; j < 2; j++) { a1[i][j] = fz; a3[i][j] = fz; }
  for (int kb = 0; kb < 4; kb++) {
    int k0 = kb << 6;
    for (int i = 0; i < 4; i++) {
      int c = i * 256 + t; int r = c >> 3; int g = (c & 7) ^ (r & 7);
      int tk = tok[slot0 + r]; int row = (tk < 0) ? 0 : tk;
      gload16(flat + (size_t)row * NC + k0 + g * 8, sA + (size_t)c * 8);
    }
    for (int i = 0; i < 2; i++) {
      int c = i * 256 + t; int r = c >> 3; int g = (c & 7) ^ (r & 7);
      gload16(B1 + (size_t)(n0 + r) * NC + k0 + g * 8, sB1 + (size_t)c * 8);
      gload16(B3 + (size_t)(n0 + r) * NC + k0 + g * 8, sB3 + (size_t)c * 8);
    }
    __syncthreads();
    for (int kk = 0; kk < 2; kk++) {
      int gq = kk * 4 + quad;
      bf16x8 af[4], b1f[2], b3f[2];
      for (int mi = 0; mi < 4; mi++) { int row = wm + mi * 16 + lq; af[mi] = *(const bf16x8*)(sA + (row * 8 + (gq ^ (row & 7))) * 8); }
      for (int ni = 0; ni < 2; ni++) {
        int row = wn + ni * 16 + lq;
        b1f[ni] = *(const bf16x8*)(sB1 + (row * 8 + (gq ^ (row & 7))) * 8);
        b3f[ni] = *(const bf16x8*)(sB3 + (row * 8 + (gq ^ (row & 7))) * 8);
      }
      for (int mi = 0; mi < 4; mi++)
        for (int ni = 0; ni < 2; ni++) {
          a1[mi][ni] = __builtin_amdgcn_mfma_f32_16x16x32_bf16(af[mi], b1f[ni], a1[mi][ni], 0, 0, 0);
          a3[mi][ni] = __builtin_amdgcn_mfma_f32_16x16x32_bf16(af[mi], b3f[ni], a3[mi][ni], 0, 0, 0);
        }
    }
    __syncthreads();
  }
  for (int mi = 0; mi < 4; mi++)
    for (int ni = 0; ni < 2; ni++) {
      int gn = n0 + wn + ni * 16 + lq;
      for (int r = 0; r < 4; r++) {
        int slot = slot0 + wm + mi * 16 + quad * 4 + r;
        float v1 = a1[mi][ni][r], v3 = a3[mi][ni][r];
        float hv = v1 / (1.f + __expf(-v1)) * v3;
        hh[(size_t)slot * NHIDP + gn] = f2bf(hv);
      }
    }
}

// ---------------- MoE expert GEMM 2: xo[tok] += w_slot * (hh @ w2^T) ----------------
__global__ __launch_bounds__(256) void k_moe_e2(const u16t* __restrict__ hh,
                                                const u16t* __restrict__ w2p,
                                                const int* __restrict__ offs,
                                                const int* __restrict__ tok,
                                                const float* __restrict__ tokw,
                                                float* __restrict__ xo) {
  __shared__ __align__(16) u16t sA[128 * 64];
  __shared__ __align__(16) u16t sB[128 * 64];
  int t = threadIdx.x;
  int slot0 = blockIdx.y * 128, n0 = blockIdx.x * 128;
  int e = 7;
  for (int i = 0; i < 8; i++) { if (slot0 < offs[i + 1]) { e = i; break; } }
  const u16t* Bw = w2p + (size_t)e * NC * NHIDP;
  int w = t >> 6, l = t & 63, quad = l >> 4, lq = l & 15;
  int wm = (w >> 1) * 64, wn = (w & 1) * 64;
  const f32x4 fz = {0.f, 0.f, 0.f, 0.f};
  f32x4 acc[4][4];
  for (int i = 0; i < 4; i++) for (int j = 0; j < 4; j++) acc[i][j] = fz;
  for (int kb = 0; kb < 11; kb++) {   // K = 704
    int k0 = kb << 6;
    for (int i = 0; i < 4; i++) {
      int c = i * 256 + t; int r = c >> 3; int g = (c & 7) ^ (r & 7);
      gload16(hh + (size_t)(slot0 + r) * NHIDP + k0 + g * 8, sA + (size_t)c * 8);
      gload16(Bw + (size_t)(n0 + r) * NHIDP + k0 + g * 8, sB + (size_t)c * 8);
    }
    __syncthreads();
    for (int kk = 0; kk < 2; kk++) {
      int gq = kk * 4 + quad;
      bf16x8 af[4], bf[4];
      for (int mi = 0; mi < 4; mi++) { int row = wm + mi * 16 + lq; af[mi] = *(const bf16x8*)(sA + (row * 8 + (gq ^ (row & 7))) * 8); }
      for (int ni = 0; ni < 4; ni++) { int row = wn + ni * 16 + lq; bf[ni] = *(const bf16x8*)(sB + (row * 8 + (gq ^ (row & 7))) * 8); }
      for (int mi = 0; mi < 4; mi++)
        for (int ni = 0; ni < 4; ni++)
          acc[mi][ni] = __builtin_amdgcn_mfma_f32_16x16x32_bf16(af[mi], bf[ni], acc[mi][ni], 0, 0, 0);
    }
    __syncthreads();
  }
  for (int mi = 0; mi < 4; mi++)
    for (int r = 0; r < 4; r++) {
      int slot = slot0 + wm + mi * 16 + quad * 4 + r;
      int tk = tok[slot];
      if (tk >= 0) {
        float wgt = tokw[slot];
        for (int ni = 0; ni < 4; ni++) {
          int gn = n0 + wn + ni * 16 + lq;
          atomicAdd(&xo[(size_t)tk * NC + gn], wgt * acc[mi][ni][r]);
        }
      }
    }
}

extern "C" void kernel_launch(void* const* d_in, const int* in_sizes, int n_in,
                              void* d_out, int out_size, void* d_ws, size_t ws_size,
                              hipStream_t stream) {
  (void)in_sizes; (void)n_in; (void)out_size; (void)ws_size;
  const float* x    = (const float*)d_in[0];
  const float* ln1w = (const float*)d_in[1];
  const float* ln2w = (const float*)d_in[2];
  const float* wq   = (const float*)d_in[3];
  const float* wk   = (const float*)d_in[4];
  const float* wv   = (const float*)d_in[5];
  const float* wo   = (const float*)d_in[6];
  const float* rw   = (const float*)d_in[7];
  const float* w1   = (const float*)d_in[8];
  const float* w2   = (const float*)d_in[9];
  const float* w3   = (const float*)d_in[10];
  float* xo = (float*)d_out;   // doubles as x2 residual buffer

  char* ws = (char*)d_ws;
  size_t off = 0;
  int* ctrl  = (int*)(ws + off);  off += 4096;
  int* eidx  = (int*)(ws + off);  off += (size_t)NTOK * 2 * 4;
  float* ew  = (float*)(ws + off); off += (size_t)NTOK * 2 * 4;
  int* tok   = (int*)(ws + off);  off += (size_t)NSLOT * 4;
  float* tokw = (float*)(ws + off); off += (size_t)NSLOT * 4;
  u16t* wqb  = (u16t*)(ws + off); off += (size_t)256 * 256 * 2;
  u16t* wkb  = (u16t*)(ws + off); off += (size_t)128 * 256 * 2;
  u16t* wvb  = (u16t*)(ws + off); off += (size_t)128 * 256 * 2;
  u16t* wob  = (u16t*)(ws + off); off += (size_t)256 * 256 * 2;
  u16t* w1p  = (u16t*)(ws + off); off += (size_t)8 * NHIDP * NC * 2;
  u16t* w3p  = (u16t*)(ws + off); off += (size_t)8 * NHIDP * NC * 2;
  u16t* w2p  = (u16t*)(ws + off); off += (size_t)8 * NC * NHIDP * 2;
  u16t* h    = (u16t*)(ws + off); off += (size_t)NTOK * NC * 2;
  u16t* q    = (u16t*)(ws + off); off += (size_t)NTOK * NC * 2;
  u16t* kbuf = (u16t*)(ws + off); off += (size_t)NTOK * 128 * 2;
  u16t* vbuf = (u16t*)(ws + off); off += (size_t)NTOK * 128 * 2;
  u16t* y    = (u16t*)(ws + off); off += (size_t)NTOK * NC * 2;
  u16t* flat = (u16t*)(ws + off); off += (size_t)NTOK * NC * 2;
  u16t* hh   = (u16t*)(ws + off); off += (size_t)NSLOT * NHIDP * 2;
  int* cnt = ctrl; int* offs = ctrl + 8; int* cursor = ctrl + 20;

  k_init<<<NSLOT / 256, 256, 0, stream>>>(tok, tokw, ctrl);
  k_cvt<<<256, 256, 0, stream>>>(wq, wqb, 65536);
  k_cvt<<<128, 256, 0, stream>>>(wk, wkb, 32768);
  k_cvt<<<128, 256, 0, stream>>>(wv, wvb, 32768);
  k_cvt<<<256, 256, 0, stream>>>(wo, wob, 65536);
  k_pack13<<<(8 * NHIDP * NC) / 256, 256, 0, stream>>>(w1, w3, w1p, w3p);
  k_pack2<<<(8 * NC * NHIDP) / 256, 256, 0, stream>>>(w2, w2p);

  k_rms<<<NTOK, 64, 0, stream>>>(x, ln1w, h);
  k_gemm_bt<<<dim3(2, NTOK / 128), 256, 0, stream>>>(h, wqb, q, NC, 256);
  k_gemm_bt<<<dim3(1, NTOK / 128), 256, 0, stream>>>(h, wkb, kbuf, NC, 128);
  k_gemm_bt<<<dim3(1, NTOK / 128), 256, 0, stream>>>(h, wvb, vbuf, NC, 128);
  k_rope<<<NTOK, 192, 0, stream>>>(q, kbuf);
  k_attn<<<dim3(3, 4, NBATCH), 256, 0, stream>>>(q, kbuf, vbuf, y);
  k_gemm_wo<<<dim3(2, NTOK / 128), 256, 0, stream>>>(y, wob, x, xo);

  k_rms<<<NTOK, 64, 0, stream>>>(xo, ln2w, flat);
  k_router<<<NTOK, 64, 0, stream>>>(xo, ln2w, rw, eidx, ew, cnt);
  k_scan<<<1, 64, 0, stream>>>(cnt, offs, cursor);
  k_scatter<<<NTOK / 256, 256, 0, stream>>>(eidx, ew, cursor, tok, tokw);
  k_moe_e1<<<dim3(11, NSLOT / 128), 256, 0, stream>>>(flat, w1p, w3p, offs, tok, hh);
  k_moe_e2<<<dim3(2, NSLOT / 128), 256, 0, stream>>>(hh, w2p, offs, tok, tokw, xo);
}

// Round 3
// 386.329 us; speedup vs baseline: 2.9129x; 2.9129x over previous
//
#include <hip/hip_runtime.h>
#include <hip/hip_bf16.h>
#include <math.h>

typedef unsigned short u16t;
typedef __bf16 bf16x8 __attribute__((ext_vector_type(8)));
typedef float f32x4 __attribute__((ext_vector_type(4)));

#define NBATCH 64
#define NT 384
#define NC 256
#define NHID 682
#define NHIDP 704
#define NTOK (NBATCH * NT)          // 24576
#define NSLOT (2 * NTOK + 1024)     // 50176 (128-padded expert regions worst case)

static __device__ __forceinline__ float bf2f(u16t u) { return __uint_as_float(((unsigned int)u) << 16); }
static __device__ __forceinline__ u16t f2bf(float f) { return __builtin_bit_cast(u16t, __float2bfloat16(f)); }

// async global->LDS, 16B per lane; LDS dest = wave-uniform base + lane*16.
static __device__ __forceinline__ void gload16(const void* gp, void* lp) {
  __builtin_amdgcn_global_load_lds((const __attribute__((address_space(1))) void*)gp,
                                   (__attribute__((address_space(3))) void*)lp, 16, 0, 0);
}

// LDS tile layout: 16B chunks, chunk(row,g) = row*8 + (g ^ (row&7)) (XOR swizzle).

// ---------------- fp32 -> bf16 elementwise convert ----------------
__global__ void k_cvt(const float* __restrict__ src, u16t* __restrict__ dst, int n) {
  int i = blockIdx.x * 256 + threadIdx.x;
  if (i < n) dst[i] = f2bf(src[i]);
}

// ---------------- RMSNorm (fp32 in, bf16 out), 4 tokens per 256-thr block ----------------
__global__ __launch_bounds__(256) void k_rms(const float* __restrict__ xin,
                                             const float* __restrict__ wg,
                                             u16t* __restrict__ out) {
  int w = threadIdx.x >> 6, l = threadIdx.x & 63;
  int n = blockIdx.x * 4 + w;
  const float* xr = xin + (size_t)n * NC;
  float4 xa = *(const float4*)(xr + l * 4);
  float ssq = xa.x * xa.x + xa.y * xa.y + xa.z * xa.z + xa.w * xa.w;
  for (int d = 1; d < 64; d <<= 1) ssq += __shfl_xor(ssq, d, 64);
  float rs = rsqrtf(ssq * (1.f / 256.f) + 1e-6f);
  float4 wa = *(const float4*)(wg + l * 4);
  ushort4 o;
  o.x = f2bf(xa.x * rs * wa.x);
  o.y = f2bf(xa.y * rs * wa.y);
  o.z = f2bf(xa.z * rs * wa.z);
  o.w = f2bf(xa.w * rs * wa.w);
  *(ushort4*)(out + (size_t)n * NC + l * 4) = o;
}

// ---------------- fused RMSNorm + router (fp32), 4 tokens per 256-thr block ----------------
// writes flat (bf16 rmsnormed), eidx, ew. No atomics.
__global__ __launch_bounds__(256) void k_rms_router(const float* __restrict__ xin,
                                                    const float* __restrict__ wg,
                                                    const float* __restrict__ rw,
                                                    u16t* __restrict__ flat,
                                                    int* __restrict__ eidx,
                                                    float* __restrict__ ew) {
  int w = threadIdx.x >> 6, l = threadIdx.x & 63;
  int n = blockIdx.x * 4 + w;
  const float* xr = xin + (size_t)n * NC;
  float4 xa = *(const float4*)(xr + l * 4);
  float ssq = xa.x * xa.x + xa.y * xa.y + xa.z * xa.z + xa.w * xa.w;
  for (int d = 1; d < 64; d <<= 1) ssq += __shfl_xor(ssq, d, 64);
  float rs = rsqrtf(ssq * (1.f / 256.f) + 1e-6f);
  float4 wa = *(const float4*)(wg + l * 4);
  float n0 = xa.x * rs * wa.x, n1 = xa.y * rs * wa.y;
  float n2 = xa.z * rs * wa.z, n3 = xa.w * rs * wa.w;
  ushort4 o; o.x = f2bf(n0); o.y = f2bf(n1); o.z = f2bf(n2); o.w = f2bf(n3);
  *(ushort4*)(flat + (size_t)n * NC + l * 4) = o;
  float acc[8];
  for (int e = 0; e < 8; e++) {
    float4 ra = *(const float4*)(rw + (size_t)e * NC + l * 4);
    acc[e] = n0 * ra.x + n1 * ra.y + n2 * ra.z + n3 * ra.w;
  }
  for (int e = 0; e < 8; e++)
    for (int d = 1; d < 64; d <<= 1) acc[e] += __shfl_xor(acc[e], d, 64);
  if (l == 0) {
    float mx = acc[0];
    for (int e = 1; e < 8; e++) mx = fmaxf(mx, acc[e]);
    float p[8], sum = 0.f;
    for (int e = 0; e < 8; e++) { p[e] = __expf(acc[e] - mx); sum += p[e]; }
    float inv = 1.f / sum;
    for (int e = 0; e < 8; e++) p[e] *= inv;
    int i0 = 0; float b0 = p[0];
    for (int e = 1; e < 8; e++) if (p[e] > b0) { b0 = p[e]; i0 = e; }
    int i1 = -1; float b1 = -1.f;
    for (int e = 0; e < 8; e++) if (e != i0 && p[e] > b1) { b1 = p[e]; i1 = e; }
    float s2 = 1.f / (b0 + b1 + 1e-9f);
    eidx[n * 2] = i0; eidx[n * 2 + 1] = i1;
    ew[n * 2] = b0 * s2; ew[n * 2 + 1] = b1 * s2;
  }
}

// ---------------- expert-count histogram: 48 blocks x 1024 entries ----------------
__global__ __launch_bounds__(256) void k_hist(const int* __restrict__ eidx, int* __restrict__ cnt) {
  __shared__ int lh[8];
  if (threadIdx.x < 8) lh[threadIdx.x] = 0;
  __syncthreads();
  int base = blockIdx.x * 1024 + threadIdx.x;
  for (int i = 0; i < 4; i++) atomicAdd(&lh[eidx[base + i * 256]], 1);
  __syncthreads();
  if (threadIdx.x < 8) atomicAdd(&cnt[threadIdx.x], lh[threadIdx.x]);
}

// ---------------- plain GEMM: C_bf16[M,N] = A[M,K] @ B[N,K]^T ----------------
__global__ __launch_bounds__(256) void k_gemm_bt(const u16t* __restrict__ A,
                                                 const u16t* __restrict__ Bw,
                                                 u16t* __restrict__ Co, int K, int N) {
  __shared__ __align__(16) u16t sA[128 * 64];
  __shared__ __align__(16) u16t sB[128 * 64];
  int t = threadIdx.x;
  int m0 = blockIdx.y * 128, n0 = blockIdx.x * 128;
  int w = t >> 6, l = t & 63, quad = l >> 4, lq = l & 15;
  int wm = (w >> 1) * 64, wn = (w & 1) * 64;
  const f32x4 fz = {0.f, 0.f, 0.f, 0.f};
  f32x4 acc[4][4];
  for (int i = 0; i < 4; i++) for (int j = 0; j < 4; j++) acc[i][j] = fz;
  int nk = K >> 6;
  for (int kb = 0; kb < nk; kb++) {
    int k0 = kb << 6;
    for (int i = 0; i < 4; i++) {
      int c = i * 256 + t; int r = c >> 3; int g = (c & 7) ^ (r & 7);
      gload16(A + (size_t)(m0 + r) * K + k0 + g * 8, sA + (size_t)c * 8);
      gload16(Bw + (size_t)(n0 + r) * K + k0 + g * 8, sB + (size_t)c * 8);
    }
    __syncthreads();
    for (int kk = 0; kk < 2; kk++) {
      int gq = kk * 4 + quad;
      bf16x8 af[4], bf[4];
      for (int mi = 0; mi < 4; mi++) { int row = wm + mi * 16 + lq; af[mi] = *(const bf16x8*)(sA + (row * 8 + (gq ^ (row & 7))) * 8); }
      for (int ni = 0; ni < 4; ni++) { int row = wn + ni * 16 + lq; bf[ni] = *(const bf16x8*)(sB + (row * 8 + (gq ^ (row & 7))) * 8); }
      for (int mi = 0; mi < 4; mi++)
        for (int ni = 0; ni < 4; ni++)
          acc[mi][ni] = __builtin_amdgcn_mfma_f32_16x16x32_bf16(af[mi], bf[ni], acc[mi][ni], 0, 0, 0);
    }
    __syncthreads();
  }
  for (int mi = 0; mi < 4; mi++)
    for (int ni = 0; ni < 4; ni++) {
      int gn = n0 + wn + ni * 16 + lq;
      for (int r = 0; r < 4; r++) {
        int gm = m0 + wm + mi * 16 + quad * 4 + r;
        Co[(size_t)gm * N + gn] = f2bf(acc[mi][ni][r]);
      }
    }
}

// ---------------- GEMM + residual: xo_f32 = y @ wo^T + x_f32 ----------------
__global__ __launch_bounds__(256) void k_gemm_wo(const u16t* __restrict__ A,
                                                 const u16t* __restrict__ Bw,
                                                 const float* __restrict__ xin,
                                                 float* __restrict__ xo) {
  __shared__ __align__(16) u16t sA[128 * 64];
  __shared__ __align__(16) u16t sB[128 * 64];
  int t = threadIdx.x;
  int m0 = blockIdx.y * 128, n0 = blockIdx.x * 128;
  int w = t >> 6, l = t & 63, quad = l >> 4, lq = l & 15;
  int wm = (w >> 1) * 64, wn = (w & 1) * 64;
  const f32x4 fz = {0.f, 0.f, 0.f, 0.f};
  f32x4 acc[4][4];
  for (int i = 0; i < 4; i++) for (int j = 0; j < 4; j++) acc[i][j] = fz;
  for (int kb = 0; kb < 4; kb++) {
    int k0 = kb << 6;
    for (int i = 0; i < 4; i++) {
      int c = i * 256 + t; int r = c >> 3; int g = (c & 7) ^ (r & 7);
      gload16(A + (size_t)(m0 + r) * NC + k0 + g * 8, sA + (size_t)c * 8);
      gload16(Bw + (size_t)(n0 + r) * NC + k0 + g * 8, sB + (size_t)c * 8);
    }
    __syncthreads();
    for (int kk = 0; kk < 2; kk++) {
      int gq = kk * 4 + quad;
      bf16x8 af[4], bf[4];
      for (int mi = 0; mi < 4; mi++) { int row = wm + mi * 16 + lq; af[mi] = *(const bf16x8*)(sA + (row * 8 + (gq ^ (row & 7))) * 8); }
      for (int ni = 0; ni < 4; ni++) { int row = wn + ni * 16 + lq; bf[ni] = *(const bf16x8*)(sB + (row * 8 + (gq ^ (row & 7))) * 8); }
      for (int mi = 0; mi < 4; mi++)
        for (int ni = 0; ni < 4; ni++)
          acc[mi][ni] = __builtin_amdgcn_mfma_f32_16x16x32_bf16(af[mi], bf[ni], acc[mi][ni], 0, 0, 0);
    }
    __syncthreads();
  }
  for (int mi = 0; mi < 4; mi++)
    for (int ni = 0; ni < 4; ni++) {
      int gn = n0 + wn + ni * 16 + lq;
      for (int r = 0; r < 4; r++) {
        int gm = m0 + wm + mi * 16 + quad * 4 + r;
        xo[(size_t)gm * NC + gn] = acc[mi][ni][r] + xin[(size_t)gm * NC + gn];
      }
    }
}

// ---------------- RoPE in place on q[N,256] and k[N,128] (bf16) ----------------
__global__ __launch_bounds__(192) void k_rope(u16t* __restrict__ q, u16t* __restrict__ kbuf) {
  int n = blockIdx.x; int t = n % NT;
  int i = threadIdx.x;
  u16t* base; int d;
  if (i < 128) { base = q + (size_t)n * NC + (i >> 5) * 64; d = i & 31; }
  else { int j = i - 128; base = kbuf + (size_t)n * 128 + (j >> 5) * 64; d = j & 31; }
  float x1 = bf2f(base[d]), x2 = bf2f(base[d + 32]);
  float ang = (float)t * powf(10000.f, -(float)d * (1.f / 32.f));
  float s, c; sincosf(ang, &s, &c);
  base[d] = f2bf(x1 * c - x2 * s);
  base[d + 32] = f2bf(x2 * c + x1 * s);
}

// ---------------- flash attention, causal GQA (bf16) ----------------
__global__ __launch_bounds__(256) void k_attn(const u16t* __restrict__ q,
                                              const u16t* __restrict__ kbuf,
                                              const u16t* __restrict__ vbuf,
                                              u16t* __restrict__ y) {
  __shared__ __align__(16) u16t sK[64 * 64];
  __shared__ __align__(16) u16t sVT[64 * 64];
  __shared__ __align__(16) u16t sP[4 * 32 * 64];
  int qt = blockIdx.x, h = blockIdx.y, b = blockIdx.z;
  int kvh = h >> 1;
  int t = threadIdx.x, w = t >> 6, l = t & 63, quad = l >> 4, lq = l & 15;
  int tb = qt * 128 + w * 32;
  bf16x8 qf[2][2];
  for (int mi = 0; mi < 2; mi++)
    for (int kk = 0; kk < 2; kk++)
      qf[mi][kk] = *(const bf16x8*)(q + ((size_t)(b * NT + tb + mi * 16 + lq)) * NC + h * 64 + kk * 32 + quad * 8);
  const f32x4 fz = {0.f, 0.f, 0.f, 0.f};
  f32x4 accO[2][4];
  float mrow[2][4], lrow[2][4];
  for (int mi = 0; mi < 2; mi++)
    for (int ni = 0; ni < 4; ni++) accO[mi][ni] = fz;
  for (int mi = 0; mi < 2; mi++)
    for (int r = 0; r < 4; r++) { mrow[mi][r] = -1e30f; lrow[mi][r] = 0.f; }
  u16t* myP = sP + w * 2048;
  int nkt = (qt + 1) * 2;
  for (int kt = 0; kt < nkt; kt++) {
    int s0 = kt * 64;
    for (int i = 0; i < 2; i++) {
      int c = i * 256 + t; int s = c >> 3; int g = (c & 7) ^ (s & 7);
      gload16(kbuf + ((size_t)(b * NT + s0 + s)) * 128 + kvh * 64 + g * 8, sK + (size_t)c * 8);
    }
    for (int i = 0; i < 2; i++) {
      int p = i * 256 + t; int n0g = p >> 6; int s = p & 63; int n0 = n0g * 8;
      const u16t* vp = vbuf + ((size_t)(b * NT + s0 + s)) * 128 + kvh * 64 + n0;
      ushort4 v0 = *(const ushort4*)vp; ushort4 v1 = *(const ushort4*)(vp + 4);
      u16t vv[8] = {v0.x, v0.y, v0.z, v0.w, v1.x, v1.y, v1.z, v1.w};
      for (int j = 0; j < 8; j++) {
        int nn = n0 + j;
        sVT[(nn * 8 + ((s >> 3) ^ (nn & 7))) * 8 + (s & 7)] = vv[j];
      }
    }
    __syncthreads();
    if (s0 <= tb + 31) {
      f32x4 accS[2][4];
      for (int mi = 0; mi < 2; mi++) for (int ni = 0; ni < 4; ni++) accS[mi][ni] = fz;
      for (int kk = 0; kk < 2; kk++) {
        int gq = kk * 4 + quad;
        bf16x8 kf[4];
        for (int ni = 0; ni < 4; ni++) { int row = ni * 16 + lq; kf[ni] = *(const bf16x8*)(sK + (row * 8 + (gq ^ (row & 7))) * 8); }
        for (int mi = 0; mi < 2; mi++)
          for (int ni = 0; ni < 4; ni++)
            accS[mi][ni] = __builtin_amdgcn_mfma_f32_16x16x32_bf16(qf[mi][kk], kf[ni], accS[mi][ni], 0, 0, 0);
      }
      for (int mi = 0; mi < 2; mi++) {
        float alpha[4];
        for (int r = 0; r < 4; r++) {
          int trow = tb + mi * 16 + quad * 4 + r;
          float mx = -1e30f;
          for (int ni = 0; ni < 4; ni++) {
            int ss = s0 + ni * 16 + lq;
            float sv = accS[mi][ni][r] * 0.125f;
            sv = (ss > trow) ? -1e30f : sv;
            accS[mi][ni][r] = sv;
            mx = fmaxf(mx, sv);
          }
          for (int d = 1; d < 16; d <<= 1) mx = fmaxf(mx, __shfl_xor(mx, d, 64));
          float mnew = fmaxf(mrow[mi][r], mx);
          float al = __expf(mrow[mi][r] - mnew);
          float rsum = 0.f;
          for (int ni = 0; ni < 4; ni++) {
            float p = __expf(accS[mi][ni][r] - mnew);
            accS[mi][ni][r] = p;
            rsum += p;
          }
          for (int d = 1; d < 16; d <<= 1) rsum += __shfl_xor(rsum, d, 64);
          lrow[mi][r] = lrow[mi][r] * al + rsum;
          mrow[mi][r] = mnew;
          alpha[r] = al;
        }
        for (int ni = 0; ni < 4; ni++)
          for (int r = 0; r < 4; r++) accO[mi][ni][r] *= alpha[r];
        for (int ni = 0; ni < 4; ni++) {
          int cc = ni * 16 + lq;
          for (int r = 0; r < 4; r++) {
            int row = mi * 16 + quad * 4 + r;
            myP[((cc >> 3) * 32 + row) * 8 + (cc & 7)] = f2bf(accS[mi][ni][r]);
          }
        }
      }
      asm volatile("s_waitcnt lgkmcnt(0)" ::: "memory");
      for (int kk = 0; kk < 2; kk++) {
        int gq = kk * 4 + quad;
        bf16x8 pf[2], vf[4];
        for (int mi = 0; mi < 2; mi++) { int row = mi * 16 + lq; pf[mi] = *(const bf16x8*)(myP + (gq * 32 + row) * 8); }
        for (int ni = 0; ni < 4; ni++) { int row = ni * 16 + lq; vf[ni] = *(const bf16x8*)(sVT + (row * 8 + (gq ^ (row & 7))) * 8); }
        for (int mi = 0; mi < 2; mi++)
          for (int ni = 0; ni < 4; ni++)
            accO[mi][ni] = __builtin_amdgcn_mfma_f32_16x16x32_bf16(pf[mi], vf[ni], accO[mi][ni], 0, 0, 0);
      }
    }
    __syncthreads();
  }
  for (int mi = 0; mi < 2; mi++)
    for (int r = 0; r < 4; r++) {
      int trow = tb + mi * 16 + quad * 4 + r;
      float inv = 1.f / lrow[mi][r];
      for (int ni = 0; ni < 4; ni++) {
        int d = ni * 16 + lq;
        y[((size_t)(b * NT + trow)) * NC + h * 64 + d] = f2bf(accO[mi][ni][r] * inv);
      }
    }
}

__global__ void k_init(int* __restrict__ tok, float* __restrict__ tokw, int* __restrict__ ctrl) {
  int i = blockIdx.x * 256 + threadIdx.x;
  if (i < NSLOT) { tok[i] = -1; tokw[i] = 0.f; }
  if (blockIdx.x == 0 && threadIdx.x < 64) ctrl[threadIdx.x] = 0;
}

__global__ void k_scan(const int* __restrict__ cnt, int* __restrict__ offs, int* __restrict__ cursor) {
  if (threadIdx.x == 0) {
    int off = 0;
    for (int e = 0; e < 8; e++) {
      offs[e] = off; cursor[e] = off;
      off += ((cnt[e] + 127) >> 7) << 7;
    }
    offs[8] = off;
  }
}

// ---------------- block-aggregated scatter: 8 reservation atomics per block ----------------
__global__ __launch_bounds__(256) void k_scatter(const int* __restrict__ eidx, const float* __restrict__ ew,
                                                 int* __restrict__ cursor, int* __restrict__ tok,
                                                 float* __restrict__ tokw) {
  __shared__ int lcnt[8], lbase[8];
  if (threadIdx.x < 8) lcnt[threadIdx.x] = 0;
  __syncthreads();
  int n = blockIdx.x * 256 + threadIdx.x;
  int e0 = eidx[n * 2], e1 = eidx[n * 2 + 1];
  int p0 = atomicAdd(&lcnt[e0], 1);
  int p1 = atomicAdd(&lcnt[e1], 1);
  __syncthreads();
  if (threadIdx.x < 8) lbase[threadIdx.x] = atomicAdd(&cursor[threadIdx.x], lcnt[threadIdx.x]);
  __syncthreads();
  int g0 = lbase[e0] + p0, g1 = lbase[e1] + p1;
  tok[g0] = n; tokw[g0] = ew[n * 2];
  tok[g1] = n; tokw[g1] = ew[n * 2 + 1];
}

// pack fp32 w1/w3 -> bf16 [8][704][256] zero-padded rows; w2 -> bf16 [8][256][704] zero-padded cols
__global__ void k_pack13(const float* __restrict__ w1, const float* __restrict__ w3,
                         u16t* __restrict__ w1p, u16t* __restrict__ w3p) {
  int idx = blockIdx.x * 256 + threadIdx.x;
  int kcol = idx & 255; int tmp = idx >> 8; int nrow = tmp % NHIDP; int e = tmp / NHIDP;
  if (nrow < NHID) {
    size_t src = ((size_t)e * NHID + nrow) * NC + kcol;
    w1p[idx] = f2bf(w1[src]); w3p[idx] = f2bf(w3[src]);
  } else { w1p[idx] = 0; w3p[idx] = 0; }
}

__global__ void k_pack2(const float* __restrict__ w2, u16t* __restrict__ w2p) {
  int idx = blockIdx.x * 256 + threadIdx.x;
  int kcol = idx % NHIDP; int tmp = idx / NHIDP; int nrow = tmp & 255; int e = tmp >> 8;
  w2p[idx] = (kcol < NHID) ? f2bf(w2[((size_t)e * NC + nrow) * NHID + kcol]) : (u16t)0;
}

// ---------------- MoE expert GEMM 1: hh = silu(A@w1^T) * (A@w3^T), gathered rows ----------------
__global__ __launch_bounds__(256) void k_moe_e1(const u16t* __restrict__ flat,
                                                const u16t* __restrict__ w1p,
                                                const u16t* __restrict__ w3p,
                                                const int* __restrict__ offs,
                                                const int* __restrict__ tok,
                                                u16t* __restrict__ hh) {
  __shared__ __align__(16) u16t sA[128 * 64];
  __shared__ __align__(16) u16t sB1[64 * 64];
  __shared__ __align__(16) u16t sB3[64 * 64];
  int t = threadIdx.x;
  int slot0 = blockIdx.y * 128, n0 = blockIdx.x * 64;
  int e = 7;
  for (int i = 0; i < 8; i++) { if (slot0 < offs[i + 1]) { e = i; break; } }
  const u16t* B1 = w1p + (size_t)e * NHIDP * NC;
  const u16t* B3 = w3p + (size_t)e * NHIDP * NC;
  int w = t >> 6, l = t & 63, quad = l >> 4, lq = l & 15;
  int wm = (w >> 1) * 64, wn = (w & 1) * 32;
  const f32x4 fz = {0.f, 0.f, 0.f, 0.f};
  f32x4 a1[4][2], a3[4][2];
  for (int i = 0; i < 4; i++) for (int j = 0; j < 2; j++) { a1[i][j] = fz; a3[i][j] = fz; }
  for (int kb = 0; kb < 4; kb++) {
    int k0 = kb << 6;
    for (int i = 0; i < 4; i++) {
      int c = i * 256 + t; int r = c >> 3; int g = (c & 7) ^ (r & 7);
      int tk = tok[slot0 + r]; int row = (tk < 0) ? 0 : tk;
      gload16(flat + (size_t)row * NC + k0 + g * 8, sA + (size_t)c * 8);
    }
    for (int i = 0; i < 2; i++) {
      int c = i * 256 + t; int r = c >> 3; int g = (c & 7) ^ (r & 7);
      gload16(B1 + (size_t)(n0 + r) * NC + k0 + g * 8, sB1 + (size_t)c * 8);
      gload16(B3 + (size_t)(n0 + r) * NC + k0 + g * 8, sB3 + (size_t)c * 8);
    }
    __syncthreads();
    for (int kk = 0; kk < 2; kk++) {
      int gq = kk * 4 + quad;
      bf16x8 af[4], b1f[2], b3f[2];
      for (int mi = 0; mi < 4; mi++) { int row = wm + mi * 16 + lq; af[mi] = *(const bf16x8*)(sA + (row * 8 + (gq ^ (row & 7))) * 8); }
      for (int ni = 0; ni < 2; ni++) {
        int row = wn + ni * 16 + lq;
        b1f[ni] = *(const bf16x8*)(sB1 + (row * 8 + (gq ^ (row & 7))) * 8);
        b3f[ni] = *(const bf16x8*)(sB3 + (row * 8 + (gq ^ (row & 7))) * 8);
      }
      for (int mi = 0; mi < 4; mi++)
        for (int ni = 0; ni < 2; ni++) {
          a1[mi][ni] = __builtin_amdgcn_mfma_f32_16x16x32_bf16(af[mi], b1f[ni], a1[mi][ni], 0, 0, 0);
          a3[mi][ni] = __builtin_amdgcn_mfma_f32_16x16x32_bf16(af[mi], b3f[ni], a3[mi][ni], 0, 0, 0);
        }
    }
    __syncthreads();
  }
  for (int mi = 0; mi < 4; mi++)
    for (int ni = 0; ni < 2; ni++) {
      int gn = n0 + wn + ni * 16 + lq;
      for (int r = 0; r < 4; r++) {
        int slot = slot0 + wm + mi * 16 + quad * 4 + r;
        float v1 = a1[mi][ni][r], v3 = a3[mi][ni][r];
        float hv = v1 / (1.f + __expf(-v1)) * v3;
        hh[(size_t)slot * NHIDP + gn] = f2bf(hv);
      }
    }
}

// ---------------- MoE expert GEMM 2: xo[tok] += w_slot * (hh @ w2^T) ----------------
__global__ __launch_bounds__(256) void k_moe_e2(const u16t* __restrict__ hh,
                                                const u16t* __restrict__ w2p,
                                                const int* __restrict__ offs,
                                                const int* __restrict__ tok,
                                                const float* __restrict__ tokw,
                                                float* __restrict__ xo) {
  __shared__ __align__(16) u16t sA[128 * 64];
  __shared__ __align__(16) u16t sB[128 * 64];
  int t = threadIdx.x;
  int slot0 = blockIdx.y * 128, n0 = blockIdx.x * 128;
  int e = 7;
  for (int i = 0; i < 8; i++) { if (slot0 < offs[i + 1]) { e = i; break; } }
  const u16t* Bw = w2p + (size_t)e * NC * NHIDP;
  int w = t >> 6, l = t & 63, quad = l >> 4, lq = l & 15;
  int wm = (w >> 1) * 64, wn = (w & 1) * 64;
  const f32x4 fz = {0.f, 0.f, 0.f, 0.f};
  f32x4 acc[4][4];
  for (int i = 0; i < 4; i++) for (int j = 0; j < 4; j++) acc[i][j] = fz;
  for (int kb = 0; kb < 11; kb++) {   // K = 704
    int k0 = kb << 6;
    for (int i = 0; i < 4; i++) {
      int c = i * 256 + t; int r = c >> 3; int g = (c & 7) ^ (r & 7);
      gload16(hh + (size_t)(slot0 + r) * NHIDP + k0 + g * 8, sA + (size_t)c * 8);
      gload16(Bw + (size_t)(n0 + r) * NHIDP + k0 + g * 8, sB + (size_t)c * 8);
    }
    __syncthreads();
    for (int kk = 0; kk < 2; kk++) {
      int gq = kk * 4 + quad;
      bf16x8 af[4], bf[4];
      for (int mi = 0; mi < 4; mi++) { int row = wm + mi * 16 + lq; af[mi] = *(const bf16x8*)(sA + (row * 8 + (gq ^ (row & 7))) * 8); }
      for (int ni = 0; ni < 4; ni++) { int row = wn + ni * 16 + lq; bf[ni] = *(const bf16x8*)(sB + (row * 8 + (gq ^ (row & 7))) * 8); }
      for (int mi = 0; mi < 4; mi++)
        for (int ni = 0; ni < 4; ni++)
          acc[mi][ni] = __builtin_amdgcn_mfma_f32_16x16x32_bf16(af[mi], bf[ni], acc[mi][ni], 0, 0, 0);
    }
    __syncthreads();
  }
  for (int mi = 0; mi < 4; mi++)
    for (int r = 0; r < 4; r++) {
      int slot = slot0 + wm + mi * 16 + quad * 4 + r;
      int tk = tok[slot];
      if (tk >= 0) {
        float wgt = tokw[slot];
        for (int ni = 0; ni < 4; ni++) {
          int gn = n0 + wn + ni * 16 + lq;
          atomicAdd(&xo[(size_t)tk * NC + gn], wgt * acc[mi][ni][r]);
        }
      }
    }
}

extern "C" void kernel_launch(void* const* d_in, const int* in_sizes, int n_in,
                              void* d_out, int out_size, void* d_ws, size_t ws_size,
                              hipStream_t stream) {
  (void)in_sizes; (void)n_in; (void)out_size; (void)ws_size;
  const float* x    = (const float*)d_in[0];
  const float* ln1w = (const float*)d_in[1];
  const float* ln2w = (const float*)d_in[2];
  const float* wq   = (const float*)d_in[3];
  const float* wk   = (const float*)d_in[4];
  const float* wv   = (const float*)d_in[5];
  const float* wo   = (const float*)d_in[6];
  const float* rw   = (const float*)d_in[7];
  const float* w1   = (const float*)d_in[8];
  const float* w2   = (const float*)d_in[9];
  const float* w3   = (const float*)d_in[10];
  float* xo = (float*)d_out;   // doubles as x2 residual buffer

  char* ws = (char*)d_ws;
  size_t off = 0;
  int* ctrl  = (int*)(ws + off);  off += 4096;
  int* eidx  = (int*)(ws + off);  off += (size_t)NTOK * 2 * 4;
  float* ew  = (float*)(ws + off); off += (size_t)NTOK * 2 * 4;
  int* tok   = (int*)(ws + off);  off += (size_t)NSLOT * 4;
  float* tokw = (float*)(ws + off); off += (size_t)NSLOT * 4;
  u16t* wqb  = (u16t*)(ws + off); off += (size_t)256 * 256 * 2;
  u16t* wkb  = (u16t*)(ws + off); off += (size_t)128 * 256 * 2;
  u16t* wvb  = (u16t*)(ws + off); off += (size_t)128 * 256 * 2;
  u16t* wob  = (u16t*)(ws + off); off += (size_t)256 * 256 * 2;
  u16t* w1p  = (u16t*)(ws + off); off += (size_t)8 * NHIDP * NC * 2;
  u16t* w3p  = (u16t*)(ws + off); off += (size_t)8 * NHIDP * NC * 2;
  u16t* w2p  = (u16t*)(ws + off); off += (size_t)8 * NC * NHIDP * 2;
  u16t* h    = (u16t*)(ws + off); off += (size_t)NTOK * NC * 2;
  u16t* q    = (u16t*)(ws + off); off += (size_t)NTOK * NC * 2;
  u16t* kbuf = (u16t*)(ws + off); off += (size_t)NTOK * 128 * 2;
  u16t* vbuf = (u16t*)(ws + off); off += (size_t)NTOK * 128 * 2;
  u16t* y    = (u16t*)(ws + off); off += (size_t)NTOK * NC * 2;
  u16t* flat = (u16t*)(ws + off); off += (size_t)NTOK * NC * 2;
  u16t* hh   = (u16t*)(ws + off); off += (size_t)NSLOT * NHIDP * 2;
  int* cnt = ctrl; int* offs = ctrl + 8; int* cursor = ctrl + 20;

  k_init<<<NSLOT / 256, 256, 0, stream>>>(tok, tokw, ctrl);
  k_cvt<<<256, 256, 0, stream>>>(wq, wqb, 65536);
  k_cvt<<<128, 256, 0, stream>>>(wk, wkb, 32768);
  k_cvt<<<128, 256, 0, stream>>>(wv, wvb, 32768);
  k_cvt<<<256, 256, 0, stream>>>(wo, wob, 65536);
  k_pack13<<<(8 * NHIDP * NC) / 256, 256, 0, stream>>>(w1, w3, w1p, w3p);
  k_pack2<<<(8 * NC * NHIDP) / 256, 256, 0, stream>>>(w2, w2p);

  k_rms<<<NTOK / 4, 256, 0, stream>>>(x, ln1w, h);
  k_gemm_bt<<<dim3(2, NTOK / 128), 256, 0, stream>>>(h, wqb, q, NC, 256);
  k_gemm_bt<<<dim3(1, NTOK / 128), 256, 0, stream>>>(h, wkb, kbuf, NC, 128);
  k_gemm_bt<<<dim3(1, NTOK / 128), 256, 0, stream>>>(h, wvb, vbuf, NC, 128);
  k_rope<<<NTOK, 192, 0, stream>>>(q, kbuf);
  k_attn<<<dim3(3, 4, NBATCH), 256, 0, stream>>>(q, kbuf, vbuf, y);
  k_gemm_wo<<<dim3(2, NTOK / 128), 256, 0, stream>>>(y, wob, x, xo);

  k_rms_router<<<NTOK / 4, 256, 0, stream>>>(xo, ln2w, rw, flat, eidx, ew);
  k_hist<<<48, 256, 0, stream>>>(eidx, cnt);
  k_scan<<<1, 64, 0, stream>>>(cnt, offs, cursor);
  k_scatter<<<NTOK / 256, 256, 0, stream>>>(eidx, ew, cursor, tok, tokw);
  k_moe_e1<<<dim3(11, NSLOT / 128), 256, 0, stream>>>(flat, w1p, w3p, offs, tok, hh);
  k_moe_e2<<<dim3(2, NSLOT / 128), 256, 0, stream>>>(hh, w2p, offs, tok, tokw, xo);
}